// Round 9
// baseline (2513.300 us; speedup 1.0000x reference)
//
#include <hip/hip_runtime.h>

#ifndef __has_builtin
#define __has_builtin(x) 0
#endif

__device__ __forceinline__ float fexp2(float x) {
#if __has_builtin(__builtin_amdgcn_exp2f)
    return __builtin_amdgcn_exp2f(x);   // v_exp_f32 (2^x)
#else
    return exp2f(x);
#endif
}
__device__ __forceinline__ float flog2(float x) {
#if __has_builtin(__builtin_amdgcn_logf)
    return __builtin_amdgcn_logf(x);    // v_log_f32 (log2 x)
#else
    return log2f(x);
#endif
}

#define NMAXN 128
#define DD    64
#define MAX_ITERS 500

// -1e5 * log2(e)  (NEG surrogate in log2 domain)
#define NEG2  (-144269.50408889634f)
// -(log2(e) / eps), eps = 1e-3 : logK2 = M * LKSC
#define LKSC  (-1442.6950408889634f)
// -(eps * ln2) : out = acc * OUTSC
#define OUTSC (-6.931471805599453e-4f)

struct SmemStage {
    float A[NMAXN * 33];   // set1 chunk [128][32] padded
    float B[NMAXN * 33];   // set2 chunk
    float nA[NMAXN];       // row norms set1
    float nB[NMAXN];       // row norms set2
};
struct SmemSink {
    // U-phase partials: [row*10 + w] -> (max,sum); 16B-aligned float4 pairs.
    float2 part[NMAXN * 10];
    float  u[NMAXN];
};
union SmemU {
    SmemStage st;
    SmemSink  sk;
    // occupancy clamp: 60 KiB -> exactly 2 blocks/CU; 512 blocks = 512 slots.
    char force[61440];
};

__global__ __launch_bounds__(512, 4)
void wasserstein_kernel(const float* __restrict__ x1, const float* __restrict__ x2,
                        const int* __restrict__ sz1, const int* __restrict__ sz2,
                        float* __restrict__ out)
{
    __shared__ SmemU  sm;
    __shared__ int    soff[16];
    __shared__ float  swred[8];

    const int b    = blockIdx.x;
    const int tid  = threadIdx.x;
    const int w    = tid >> 6;        // wave 0..7
    const int lane = tid & 63;
    const int rg   = lane >> 2;       // 0..15 : rows rg + 16*r   (r = 0..7)
    const int cg   = lane & 3;        // with w: cols (w*4+cg) + 32*c (c = 0..3)
    const int cb32 = (w << 2) | cg;   // 0..31

    // ---- exclusive prefix sums of sizes (512 threads: one element each) ----
    int a1 = (tid < b) ? sz1[tid] : 0;
    int a2 = (tid < b) ? sz2[tid] : 0;
#pragma unroll
    for (int d = 1; d < 64; d <<= 1) {
        a1 += __shfl_xor(a1, d);
        a2 += __shfl_xor(a2, d);
    }
    if (lane == 0) { soff[w] = a1; soff[8 + w] = a2; }
    if (tid < NMAXN) { sm.st.nA[tid] = 0.f; sm.st.nB[tid] = 0.f; }
    __syncthreads();
    int off1 = 0, off2 = 0;
#pragma unroll
    for (int i = 0; i < 8; ++i) { off1 += soff[i]; off2 += soff[8 + i]; }
    const int n1 = sz1[b];
    const int n2 = sz2[b];
    const int rmax = (n1 + 15) >> 4;   // 4..8 row strips (stride 16)
    const int cs   = (n2 + 31) >> 5;   // 2..4 col strips (stride 32)

    // ---- stage sets in D-chunks of 32, accumulate dots + norms ----
    float lk[8][4];   // starts as dot accumulator, becomes logK2
#pragma unroll
    for (int r = 0; r < 8; ++r)
#pragma unroll
        for (int c = 0; c < 4; ++c) lk[r][c] = 0.f;

    const int srow = tid >> 2;  // 0..127
    const int sq   = tid & 3;   // 8-float slice of the 32-col chunk

    for (int ch = 0; ch < 2; ++ch) {
        const float* p1 = x1 + (size_t)(off1 + srow) * DD + ch * 32 + sq * 8;
        const float* p2 = x2 + (size_t)(off2 + srow) * DD + ch * 32 + sq * 8;
        const bool ok1 = srow < n1;
        const bool ok2 = srow < n2;
        float va[8], vb[8];
#pragma unroll
        for (int qq = 0; qq < 2; ++qq) {
            float4 t1 = ok1 ? ((const float4*)p1)[qq] : make_float4(0.f, 0.f, 0.f, 0.f);
            float4 t2 = ok2 ? ((const float4*)p2)[qq] : make_float4(0.f, 0.f, 0.f, 0.f);
            va[4*qq+0] = t1.x; va[4*qq+1] = t1.y; va[4*qq+2] = t1.z; va[4*qq+3] = t1.w;
            vb[4*qq+0] = t2.x; vb[4*qq+1] = t2.y; vb[4*qq+2] = t2.z; vb[4*qq+3] = t2.w;
        }
        float s1 = 0.f, s2 = 0.f;
#pragma unroll
        for (int j = 0; j < 8; ++j) {
            sm.st.A[srow * 33 + sq * 8 + j] = va[j];
            sm.st.B[srow * 33 + sq * 8 + j] = vb[j];
            s1 += va[j] * va[j];
            s2 += vb[j] * vb[j];
        }
        s1 += __shfl_xor(s1, 1); s1 += __shfl_xor(s1, 2);
        s2 += __shfl_xor(s2, 1); s2 += __shfl_xor(s2, 2);
        if (sq == 0) { sm.st.nA[srow] += s1; sm.st.nB[srow] += s2; }
        __syncthreads();
#pragma unroll 2
        for (int d = 0; d < 32; ++d) {
            float av[8], bv[4];
#pragma unroll
            for (int r = 0; r < 8; ++r) av[r] = sm.st.A[(rg + 16*r) * 33 + d];
#pragma unroll
            for (int c = 0; c < 4; ++c) bv[c] = sm.st.B[(cb32 + 32*c) * 33 + d];
#pragma unroll
            for (int r = 0; r < 8; ++r)
#pragma unroll
                for (int c = 0; c < 4; ++c)
                    lk[r][c] = fmaf(av[r], bv[c], lk[r][c]);
        }
        __syncthreads();
    }

    // logK2 = -M*log2e/eps, M = ||a||^2 + ||b||^2 - 2ab (clamped >= 0)
    float lb[4], mpad[4];
    const float lbv = flog2((float)n1) - flog2((float)n2);
    {
        float rn1[8], rn2[4];
#pragma unroll
        for (int r = 0; r < 8; ++r) rn1[r] = sm.st.nA[rg + 16*r];
#pragma unroll
        for (int c = 0; c < 4; ++c) rn2[c] = sm.st.nB[cb32 + 32*c];
#pragma unroll
        for (int r = 0; r < 8; ++r)
#pragma unroll
            for (int c = 0; c < 4; ++c) {
                float M = rn1[r] + rn2[c] - 2.f * lk[r][c];
                lk[r][c] = fmaxf(M, 0.f) * LKSC;
            }
#pragma unroll
        for (int c = 0; c < 4; ++c) {
            lb[c]   = (cb32 + 32*c < n2) ? lbv : NEG2;
            mpad[c] = rn2[c] * LKSC;   // iter-0 candidate from zero pad rows
        }
    }
    const float p1f = (float)(NMAXN - 16 * rmax);  // non-materialized pad rows
    __syncthreads();   // retire staging view of the union

    // ---- Sinkhorn (log2 domain); v in-lane; u via coop combine ----
    const int   crow   = tid >> 2;                  // coop-combine row 0..127
    const int   q      = tid & 3;
    const float lacrow = (crow < n1) ? 0.f : NEG2;

    float uloc[8], v[4];
#pragma unroll
    for (int r = 0; r < 8; ++r) uloc[r] = 0.f;
#pragma unroll
    for (int c = 0; c < 4; ++c) v[c] = NEG2;

    for (int k = 0; k < MAX_ITERS; ++k) {
        const bool fold = (k == 0) && (p1f > 0.5f);

        // ===== phase V (in-wave): v_c = lb_c - lse_r(lk[r][c] + u[r]) =====
#pragma unroll
        for (int c = 0; c < 4; ++c) {
            if (c < cs) {   // wave-uniform col-strip guard
                float t0 = lk[0][c] + uloc[0];
                float t1 = lk[1][c] + uloc[1];
                float t2 = lk[2][c] + uloc[2];
                float t3 = lk[3][c] + uloc[3];
                float t4, t5, t6, t7;
                float m = fmaxf(fmaxf(t0, t1), fmaxf(t2, t3));
                if (rmax > 4) { t4 = lk[4][c] + uloc[4]; m = fmaxf(m, t4);
                if (rmax > 5) { t5 = lk[5][c] + uloc[5]; m = fmaxf(m, t5);
                if (rmax > 6) { t6 = lk[6][c] + uloc[6]; m = fmaxf(m, t6);
                if (rmax > 7) { t7 = lk[7][c] + uloc[7]; m = fmaxf(m, t7); }}}}
                m = fmaxf(m, __shfl_xor(m, 4));
                m = fmaxf(m, __shfl_xor(m, 8));
                m = fmaxf(m, __shfl_xor(m, 16));
                m = fmaxf(m, __shfl_xor(m, 32));
                float s = fexp2(t0 - m) + fexp2(t1 - m)
                        + fexp2(t2 - m) + fexp2(t3 - m);
                if (rmax > 4) { s += fexp2(t4 - m);
                if (rmax > 5) { s += fexp2(t5 - m);
                if (rmax > 6) { s += fexp2(t6 - m);
                if (rmax > 7) { s += fexp2(t7 - m); }}}}
                s += __shfl_xor(s, 4);
                s += __shfl_xor(s, 8);
                s += __shfl_xor(s, 16);
                s += __shfl_xor(s, 32);
                if (fold) {   // analytic pad-row fold (u=0 at iter 0)
                    float mm = fmaxf(m, mpad[c]);
                    s = s * fexp2(m - mm) + p1f * fexp2(mpad[c] - mm);
                    m = mm;
                }
                v[c] = lb[c] - (m + flog2(s));
            }
        }

        // ===== phase U partials: per-wave (max,sum) over its 16-col slice ====
#pragma unroll
        for (int r = 0; r < 8; ++r) {
            if (r < 4 || r < rmax) {   // wave-uniform row-strip guard
                float t0 = lk[r][0] + v[0];
                float t1 = lk[r][1] + v[1];
                float t2, t3;
                float m = fmaxf(t0, t1);
                if (cs > 2) { t2 = lk[r][2] + v[2]; m = fmaxf(m, t2);
                if (cs > 3) { t3 = lk[r][3] + v[3]; m = fmaxf(m, t3); }}
                m = fmaxf(m, __shfl_xor(m, 1));
                m = fmaxf(m, __shfl_xor(m, 2));
                float s = fexp2(t0 - m) + fexp2(t1 - m);
                if (cs > 2) { s += fexp2(t2 - m);
                if (cs > 3) { s += fexp2(t3 - m); }}
                s += __shfl_xor(s, 1);
                s += __shfl_xor(s, 2);
                if ((r & 3) == cg)   // one writer per (row, wave)
                    sm.sk.part[(rg + 16*r) * 10 + w] = make_float2(m, s);
            }
        }
        __syncthreads();                               // B1

        // ===== cooperative combine (waves w < rmax cover rows < 16*rmax) ====
        if (w < rmax) {
            float4 t = *(const float4*)&sm.sk.part[crow * 10 + 2 * q];
            float m = fmaxf(t.x, t.z);
            float s = t.y * fexp2(t.x - m) + t.w * fexp2(t.z - m);
            float mo = __shfl_xor(m, 1), so = __shfl_xor(s, 1);
            float mm = fmaxf(m, mo);
            s = s * fexp2(m - mm) + so * fexp2(mo - mm); m = mm;
            mo = __shfl_xor(m, 2); so = __shfl_xor(s, 2);
            mm = fmaxf(m, mo);
            s = s * fexp2(m - mm) + so * fexp2(mo - mm); m = mm;
            if (q == 0) sm.sk.u[crow] = lacrow - (m + flog2(s));
        }
        __syncthreads();                               // B2

#pragma unroll
        for (int r = 0; r < 8; ++r)
            if (r < 4 || r < rmax)
                uloc[r] = sm.sk.u[rg + 16*r];
    }

    // ---- epilogue: out_b = OUTSC * sum_ij lk_ij * 2^(lk+u+v) ----
    float acc = 0.f;
#pragma unroll
    for (int r = 0; r < 8; ++r) {
        if (r < 4 || r < rmax) {
            acc += lk[r][0] * fexp2(lk[r][0] + uloc[r] + v[0]);
            acc += lk[r][1] * fexp2(lk[r][1] + uloc[r] + v[1]);
            if (cs > 2) { acc += lk[r][2] * fexp2(lk[r][2] + uloc[r] + v[2]);
            if (cs > 3) { acc += lk[r][3] * fexp2(lk[r][3] + uloc[r] + v[3]); }}
        }
    }
#pragma unroll
    for (int d = 1; d < 64; d <<= 1) acc += __shfl_xor(acc, d);
    if (lane == 0) swred[w] = acc;
    __syncthreads();
    if (tid == 0) {
        float s = 0.f;
#pragma unroll
        for (int i = 0; i < 8; ++i) s += swred[i];
        out[b] = s * OUTSC;
    }
}

extern "C" void kernel_launch(void* const* d_in, const int* in_sizes, int n_in,
                              void* d_out, int out_size, void* d_ws, size_t ws_size,
                              hipStream_t stream) {
    const float* x1  = (const float*)d_in[0];
    const float* x2  = (const float*)d_in[1];
    const int*   sz1 = (const int*)d_in[2];
    const int*   sz2 = (const int*)d_in[3];
    float* out = (float*)d_out;
    hipLaunchKernelGGL(wasserstein_kernel, dim3(512), dim3(512), 0, stream,
                       x1, x2, sz1, sz2, out);
}

// Round 10
// 1153.336 us; speedup vs baseline: 2.1792x; 2.1792x over previous
//
#include <hip/hip_runtime.h>

#ifndef __has_builtin
#define __has_builtin(x) 0
#endif

__device__ __forceinline__ float fexp2(float x) {
#if __has_builtin(__builtin_amdgcn_exp2f)
    return __builtin_amdgcn_exp2f(x);   // v_exp_f32 (2^x)
#else
    return exp2f(x);
#endif
}
__device__ __forceinline__ float flog2(float x) {
#if __has_builtin(__builtin_amdgcn_logf)
    return __builtin_amdgcn_logf(x);    // v_log_f32 (log2 x)
#else
    return log2f(x);
#endif
}
__device__ __forceinline__ float frcp(float x) {
#if __has_builtin(__builtin_amdgcn_rcpf)
    return __builtin_amdgcn_rcpf(x);    // v_rcp_f32 (approx; self-correcting here)
#else
    return 1.0f / x;
#endif
}

#define NMAXN 128
#define DD    64
#define MAX_ITERS 500
#define KLOG  12            // log-domain warm-up iterations

// -1e5 * log2(e)  (NEG surrogate in log2 domain)
#define NEG2  (-144269.50408889634f)
// -(log2(e) / eps), eps = 1e-3 : logK2 = M * LKSC
#define LKSC  (-1442.6950408889634f)
// -(eps * ln2) : out = acc * OUTSC   (lk * OUTSC == M exactly)
#define OUTSC (-6.931471805599453e-4f)

struct SmemStage {
    float A[NMAXN * 33];   // set1 chunk [128][32] padded
    float B[NMAXN * 33];   // set2 chunk
    float nA[NMAXN];       // row norms set1
    float nB[NMAXN];       // row norms set2
};
struct SmemSink {
    float2 plog[NMAXN * 10];  // log-phase partials: [row*10+w] -> (max,sum)
    float  ulog[NMAXN];       // log-phase u
    float  pmul[NMAXN * 10];  // mul-phase row-sum partials: [row*10+w]
    float  g[NMAXN];          // mul-phase row factors
};
union SmemU {
    SmemStage st;
    SmemSink  sk;
    // occupancy clamp: 60 KiB -> exactly 2 blocks/CU; 512 blocks = 512 slots.
    char force[61440];
};

__global__ __launch_bounds__(512, 4)
void wasserstein_kernel(const float* __restrict__ x1, const float* __restrict__ x2,
                        const int* __restrict__ sz1, const int* __restrict__ sz2,
                        float* __restrict__ out)
{
    __shared__ SmemU  sm;
    __shared__ int    soff[16];
    __shared__ float  swred[8];

    const int b    = blockIdx.x;
    const int tid  = threadIdx.x;
    const int w    = tid >> 6;        // wave 0..7
    const int lane = tid & 63;
    const int rg   = lane >> 2;       // 0..15 : rows rg + 16*r   (r = 0..7)
    const int cg   = lane & 3;        // with w: cols (w*4+cg) + 32*c (c = 0..3)
    const int cb32 = (w << 2) | cg;   // 0..31

    // ---- exclusive prefix sums of sizes (512 threads: one element each) ----
    int a1 = (tid < b) ? sz1[tid] : 0;
    int a2 = (tid < b) ? sz2[tid] : 0;
#pragma unroll
    for (int d = 1; d < 64; d <<= 1) {
        a1 += __shfl_xor(a1, d);
        a2 += __shfl_xor(a2, d);
    }
    if (lane == 0) { soff[w] = a1; soff[8 + w] = a2; }
    if (tid < NMAXN) { sm.st.nA[tid] = 0.f; sm.st.nB[tid] = 0.f; }
    __syncthreads();
    int off1 = 0, off2 = 0;
#pragma unroll
    for (int i = 0; i < 8; ++i) { off1 += soff[i]; off2 += soff[8 + i]; }
    const int n1 = sz1[b];
    const int n2 = sz2[b];

    // ---- stage sets in D-chunks of 32, accumulate dots + norms ----
    float lk[8][4];   // starts as dot accumulator, becomes logK2
#pragma unroll
    for (int r = 0; r < 8; ++r)
#pragma unroll
        for (int c = 0; c < 4; ++c) lk[r][c] = 0.f;

    const int srow = tid >> 2;  // 0..127
    const int sq   = tid & 3;   // 8-float slice of the 32-col chunk

    for (int ch = 0; ch < 2; ++ch) {
        const float* p1 = x1 + (size_t)(off1 + srow) * DD + ch * 32 + sq * 8;
        const float* p2 = x2 + (size_t)(off2 + srow) * DD + ch * 32 + sq * 8;
        const bool ok1 = srow < n1;
        const bool ok2 = srow < n2;
        float va[8], vb[8];
#pragma unroll
        for (int qq = 0; qq < 2; ++qq) {
            float4 t1 = ok1 ? ((const float4*)p1)[qq] : make_float4(0.f, 0.f, 0.f, 0.f);
            float4 t2 = ok2 ? ((const float4*)p2)[qq] : make_float4(0.f, 0.f, 0.f, 0.f);
            va[4*qq+0] = t1.x; va[4*qq+1] = t1.y; va[4*qq+2] = t1.z; va[4*qq+3] = t1.w;
            vb[4*qq+0] = t2.x; vb[4*qq+1] = t2.y; vb[4*qq+2] = t2.z; vb[4*qq+3] = t2.w;
        }
        float s1 = 0.f, s2 = 0.f;
#pragma unroll
        for (int j = 0; j < 8; ++j) {
            sm.st.A[srow * 33 + sq * 8 + j] = va[j];
            sm.st.B[srow * 33 + sq * 8 + j] = vb[j];
            s1 += va[j] * va[j];
            s2 += vb[j] * vb[j];
        }
        s1 += __shfl_xor(s1, 1); s1 += __shfl_xor(s1, 2);
        s2 += __shfl_xor(s2, 1); s2 += __shfl_xor(s2, 2);
        if (sq == 0) { sm.st.nA[srow] += s1; sm.st.nB[srow] += s2; }
        __syncthreads();
#pragma unroll 2
        for (int d = 0; d < 32; ++d) {
            float av[8], bv[4];
#pragma unroll
            for (int r = 0; r < 8; ++r) av[r] = sm.st.A[(rg + 16*r) * 33 + d];
#pragma unroll
            for (int c = 0; c < 4; ++c) bv[c] = sm.st.B[(cb32 + 32*c) * 33 + d];
#pragma unroll
            for (int r = 0; r < 8; ++r)
#pragma unroll
                for (int c = 0; c < 4; ++c)
                    lk[r][c] = fmaf(av[r], bv[c], lk[r][c]);
        }
        __syncthreads();
    }

    // logK2 = -M*log2e/eps, M = ||a||^2 + ||b||^2 - 2ab (clamped >= 0)
    float lb[4];
    const float lbv = flog2((float)n1) - flog2((float)n2);
    {
        float rn1[8], rn2[4];
#pragma unroll
        for (int r = 0; r < 8; ++r) rn1[r] = sm.st.nA[rg + 16*r];
#pragma unroll
        for (int c = 0; c < 4; ++c) rn2[c] = sm.st.nB[cb32 + 32*c];
#pragma unroll
        for (int r = 0; r < 8; ++r)
#pragma unroll
            for (int c = 0; c < 4; ++c) {
                float M = rn1[r] + rn2[c] - 2.f * lk[r][c];
                lk[r][c] = fmaxf(M, 0.f) * LKSC;
            }
#pragma unroll
        for (int c = 0; c < 4; ++c)
            lb[c] = (cb32 + 32*c < n2) ? lbv : NEG2;
    }
    __syncthreads();   // retire staging view of the union

    const int   crow   = tid >> 2;                  // coop-combine row 0..127
    const int   q      = tid & 3;
    const float lacrow = (crow < n1) ? 0.f : NEG2;

    float uloc[8], v[4];
#pragma unroll
    for (int r = 0; r < 8; ++r) uloc[r] = 0.f;

    // ================= Phase 1: KLOG log-domain iterations =================
    for (int k = 0; k < KLOG; ++k) {
        // phase V (in-wave): v_c = lb_c - lse_r(lk[r][c] + u[r])
        float mx[4], sc[4];
#pragma unroll
        for (int c = 0; c < 4; ++c) mx[c] = lk[0][c] + uloc[0];
#pragma unroll
        for (int r = 1; r < 8; ++r)
#pragma unroll
            for (int c = 0; c < 4; ++c)
                mx[c] = fmaxf(mx[c], lk[r][c] + uloc[r]);
#pragma unroll
        for (int c = 0; c < 4; ++c) {
            mx[c] = fmaxf(mx[c], __shfl_xor(mx[c], 4));
            mx[c] = fmaxf(mx[c], __shfl_xor(mx[c], 8));
            mx[c] = fmaxf(mx[c], __shfl_xor(mx[c], 16));
            mx[c] = fmaxf(mx[c], __shfl_xor(mx[c], 32));
        }
#pragma unroll
        for (int c = 0; c < 4; ++c) sc[c] = fexp2(lk[0][c] + uloc[0] - mx[c]);
#pragma unroll
        for (int r = 1; r < 8; ++r)
#pragma unroll
            for (int c = 0; c < 4; ++c)
                sc[c] += fexp2(lk[r][c] + uloc[r] - mx[c]);
#pragma unroll
        for (int c = 0; c < 4; ++c) {
            sc[c] += __shfl_xor(sc[c], 4);
            sc[c] += __shfl_xor(sc[c], 8);
            sc[c] += __shfl_xor(sc[c], 16);
            sc[c] += __shfl_xor(sc[c], 32);
        }
#pragma unroll
        for (int c = 0; c < 4; ++c)
            v[c] = lb[c] - (mx[c] + flog2(sc[c]));

        // phase U partials: per-wave (max,sum) over its 16-col slice
#pragma unroll
        for (int r = 0; r < 8; ++r) {
            float mr = lk[r][0] + v[0];
#pragma unroll
            for (int c = 1; c < 4; ++c) mr = fmaxf(mr, lk[r][c] + v[c]);
            mr = fmaxf(mr, __shfl_xor(mr, 1));
            mr = fmaxf(mr, __shfl_xor(mr, 2));
            float sr = fexp2(lk[r][0] + v[0] - mr);
#pragma unroll
            for (int c = 1; c < 4; ++c) sr += fexp2(lk[r][c] + v[c] - mr);
            sr += __shfl_xor(sr, 1);
            sr += __shfl_xor(sr, 2);
            if ((r & 3) == cg)
                sm.sk.plog[(rg + 16*r) * 10 + w] = make_float2(mr, sr);
        }
        __syncthreads();                               // B1

        {   // cooperative combine: 4 lanes per row fold 8 (m,s) partials
            float4 t = *(const float4*)&sm.sk.plog[crow * 10 + 2 * q];
            float m = fmaxf(t.x, t.z);
            float s = t.y * fexp2(t.x - m) + t.w * fexp2(t.z - m);
            float mo = __shfl_xor(m, 1), so = __shfl_xor(s, 1);
            float mm = fmaxf(m, mo);
            s = s * fexp2(m - mm) + so * fexp2(mo - mm); m = mm;
            mo = __shfl_xor(m, 2); so = __shfl_xor(s, 2);
            mm = fmaxf(m, mo);
            s = s * fexp2(m - mm) + so * fexp2(mo - mm); m = mm;
            if (q == 0) sm.sk.ulog[crow] = lacrow - (m + flog2(s));
        }
        __syncthreads();                               // B2

#pragma unroll
        for (int r = 0; r < 8; ++r) uloc[r] = sm.sk.ulog[rg + 16*r];
    }

    // ============== Transition: Q = exp2(lk + u + v) =======================
    float Q[8][4];
#pragma unroll
    for (int r = 0; r < 8; ++r)
#pragma unroll
        for (int c = 0; c < 4; ++c)
            Q[r][c] = fexp2(lk[r][c] + uloc[r] + v[c]);

    const float bmulv = (float)n1 / (float)n2;   // beta for valid cols
    float fmask[4];
#pragma unroll
    for (int c = 0; c < 4; ++c)
        fmask[c] = (cb32 + 32*c < n2) ? bmulv : 0.f;
    const float gmask = (crow < n1) ? 1.f : 0.f;

    // ============== Phase 2: multiplicative Sinkhorn =======================
    // col: S_c = sum_r Q; f_c = beta_c / S_c; Q *= f
    // row: T_r = sum_c Q; g_r = alpha_r / T_r; Q *= g
    // Underflowed Q cells are exactly the cells contributing 0.0f to the
    // log-domain fp32 sums; pads have beta/alpha = 0 -> stay exactly 0.
    for (int k = KLOG; k < MAX_ITERS; ++k) {
        float f[4];
#pragma unroll
        for (int c = 0; c < 4; ++c) {
            float s = ((Q[0][c] + Q[1][c]) + (Q[2][c] + Q[3][c]))
                    + ((Q[4][c] + Q[5][c]) + (Q[6][c] + Q[7][c]));
            s += __shfl_xor(s, 4);
            s += __shfl_xor(s, 8);
            s += __shfl_xor(s, 16);
            s += __shfl_xor(s, 32);
            f[c] = fmask[c] * frcp(fmaxf(s, 1e-37f));
        }
#pragma unroll
        for (int r = 0; r < 8; ++r)
#pragma unroll
            for (int c = 0; c < 4; ++c)
                Q[r][c] *= f[c];

#pragma unroll
        for (int r = 0; r < 8; ++r) {
            float t = (Q[r][0] + Q[r][1]) + (Q[r][2] + Q[r][3]);
            t += __shfl_xor(t, 1);
            t += __shfl_xor(t, 2);
            if ((r & 3) == cg)
                sm.sk.pmul[(rg + 16*r) * 10 + w] = t;
        }
        __syncthreads();                               // B1

        {
            float2 t2 = *(const float2*)&sm.sk.pmul[crow * 10 + 2 * q];
            float t = t2.x + t2.y;
            t += __shfl_xor(t, 1);
            t += __shfl_xor(t, 2);
            float gg = gmask * frcp(fmaxf(t, 1e-37f));
            if (q == 0) sm.sk.g[crow] = gg;
        }
        __syncthreads();                               // B2

#pragma unroll
        for (int r = 0; r < 8; ++r) {
            float gg = sm.sk.g[rg + 16*r];
#pragma unroll
            for (int c = 0; c < 4; ++c)
                Q[r][c] *= gg;
        }
    }

    // ---- epilogue: out_b = OUTSC * sum_ij lk_ij * Q_ij  (Q == P) ----
    float acc = 0.f;
#pragma unroll
    for (int r = 0; r < 8; ++r)
#pragma unroll
        for (int c = 0; c < 4; ++c)
            acc = fmaf(lk[r][c], Q[r][c], acc);
#pragma unroll
    for (int d = 1; d < 64; d <<= 1) acc += __shfl_xor(acc, d);
    if (lane == 0) swred[w] = acc;
    __syncthreads();
    if (tid == 0) {
        float s = 0.f;
#pragma unroll
        for (int i = 0; i < 8; ++i) s += swred[i];
        out[b] = s * OUTSC;
    }
}

extern "C" void kernel_launch(void* const* d_in, const int* in_sizes, int n_in,
                              void* d_out, int out_size, void* d_ws, size_t ws_size,
                              hipStream_t stream) {
    const float* x1  = (const float*)d_in[0];
    const float* x2  = (const float*)d_in[1];
    const int*   sz1 = (const int*)d_in[2];
    const int*   sz2 = (const int*)d_in[3];
    float* out = (float*)d_out;
    hipLaunchKernelGGL(wasserstein_kernel, dim3(512), dim3(512), 0, stream,
                       x1, x2, sz1, sz2, out);
}

// Round 11
// 1143.305 us; speedup vs baseline: 2.1983x; 1.0088x over previous
//
#include <hip/hip_runtime.h>

#ifndef __has_builtin
#define __has_builtin(x) 0
#endif

typedef float v2f __attribute__((ext_vector_type(2)));

__device__ __forceinline__ float fexp2(float x) {
#if __has_builtin(__builtin_amdgcn_exp2f)
    return __builtin_amdgcn_exp2f(x);   // v_exp_f32 (2^x)
#else
    return exp2f(x);
#endif
}
__device__ __forceinline__ float flog2(float x) {
#if __has_builtin(__builtin_amdgcn_logf)
    return __builtin_amdgcn_logf(x);    // v_log_f32 (log2 x)
#else
    return log2f(x);
#endif
}
__device__ __forceinline__ float frcp(float x) {
#if __has_builtin(__builtin_amdgcn_rcpf)
    return __builtin_amdgcn_rcpf(x);    // v_rcp_f32 (approx; Sinkhorn self-corrects)
#else
    return 1.0f / x;
#endif
}

#define NMAXN 128
#define DD    64
#define MAX_ITERS 500
#define KLOG  12            // log-domain warm-up iterations

// -1e5 * log2(e)  (NEG surrogate in log2 domain)
#define NEG2  (-144269.50408889634f)
// -(log2(e) / eps), eps = 1e-3 : logK2 = M * LKSC
#define LKSC  (-1442.6950408889634f)
// -(eps * ln2) : out = acc * OUTSC
#define OUTSC (-6.931471805599453e-4f)

// scalar view of the packed lk tile (c = 0..3 -> pair c>>1, half c&1)
#define LK(r, c) (((c) & 1) ? lk2[r][(c) >> 1].y : lk2[r][(c) >> 1].x)

struct SmemStage {
    float A[NMAXN * 33];   // set1 chunk [128][32] padded
    float B[NMAXN * 33];   // set2 chunk
    float nA[NMAXN];       // row norms set1
    float nB[NMAXN];       // row norms set2
};
struct SmemSink {
    float2 plog[NMAXN * 10];  // log-phase partials: [row*10+w] -> (max,sum)
    float  ulog[NMAXN];       // log-phase u
    float  pmul[NMAXN * 10];  // mul-phase row-sum partials: [row*10+w]
    float  g[NMAXN];          // mul-phase row factors
};
union SmemU {
    SmemStage st;
    SmemSink  sk;
    // occupancy clamp: 60 KiB -> exactly 2 blocks/CU; 512 blocks = 512 slots.
    char force[61440];
};

__global__ __launch_bounds__(512, 4)
void wasserstein_kernel(const float* __restrict__ x1, const float* __restrict__ x2,
                        const int* __restrict__ sz1, const int* __restrict__ sz2,
                        float* __restrict__ out)
{
    __shared__ SmemU  sm;
    __shared__ int    soff[16];
    __shared__ float  swred[8];

    const int b    = blockIdx.x;
    const int tid  = threadIdx.x;
    const int w    = tid >> 6;        // wave 0..7
    const int lane = tid & 63;
    const int rg   = lane >> 2;       // 0..15 : rows rg + 16*r   (r = 0..7)
    const int cg   = lane & 3;        // with w: cols (w*4+cg) + 32*c (c = 0..3)
    const int cb32 = (w << 2) | cg;   // 0..31

    // ---- exclusive prefix sums of sizes (512 threads: one element each) ----
    int a1 = (tid < b) ? sz1[tid] : 0;
    int a2 = (tid < b) ? sz2[tid] : 0;
#pragma unroll
    for (int d = 1; d < 64; d <<= 1) {
        a1 += __shfl_xor(a1, d);
        a2 += __shfl_xor(a2, d);
    }
    if (lane == 0) { soff[w] = a1; soff[8 + w] = a2; }
    if (tid < NMAXN) { sm.st.nA[tid] = 0.f; sm.st.nB[tid] = 0.f; }
    __syncthreads();
    int off1 = 0, off2 = 0;
#pragma unroll
    for (int i = 0; i < 8; ++i) { off1 += soff[i]; off2 += soff[8 + i]; }
    const int n1 = sz1[b];
    const int n2 = sz2[b];

    // ---- stage sets in D-chunks of 32, accumulate dots + norms ----
    v2f lk2[8][2];   // packed over col pairs; starts as dot acc, becomes logK2
#pragma unroll
    for (int r = 0; r < 8; ++r)
#pragma unroll
        for (int j = 0; j < 2; ++j) { lk2[r][j].x = 0.f; lk2[r][j].y = 0.f; }

    const int srow = tid >> 2;  // 0..127
    const int sq   = tid & 3;   // 8-float slice of the 32-col chunk

    for (int ch = 0; ch < 2; ++ch) {
        const float* p1 = x1 + (size_t)(off1 + srow) * DD + ch * 32 + sq * 8;
        const float* p2 = x2 + (size_t)(off2 + srow) * DD + ch * 32 + sq * 8;
        const bool ok1 = srow < n1;
        const bool ok2 = srow < n2;
        float va[8], vb[8];
#pragma unroll
        for (int qq = 0; qq < 2; ++qq) {
            float4 t1 = ok1 ? ((const float4*)p1)[qq] : make_float4(0.f, 0.f, 0.f, 0.f);
            float4 t2 = ok2 ? ((const float4*)p2)[qq] : make_float4(0.f, 0.f, 0.f, 0.f);
            va[4*qq+0] = t1.x; va[4*qq+1] = t1.y; va[4*qq+2] = t1.z; va[4*qq+3] = t1.w;
            vb[4*qq+0] = t2.x; vb[4*qq+1] = t2.y; vb[4*qq+2] = t2.z; vb[4*qq+3] = t2.w;
        }
        float s1 = 0.f, s2v = 0.f;
#pragma unroll
        for (int j = 0; j < 8; ++j) {
            sm.st.A[srow * 33 + sq * 8 + j] = va[j];
            sm.st.B[srow * 33 + sq * 8 + j] = vb[j];
            s1  += va[j] * va[j];
            s2v += vb[j] * vb[j];
        }
        s1  += __shfl_xor(s1, 1);  s1  += __shfl_xor(s1, 2);
        s2v += __shfl_xor(s2v, 1); s2v += __shfl_xor(s2v, 2);
        if (sq == 0) { sm.st.nA[srow] += s1; sm.st.nB[srow] += s2v; }
        __syncthreads();
#pragma unroll 2
        for (int d = 0; d < 32; ++d) {
            float av[8];
            v2f bv2[2];
#pragma unroll
            for (int r = 0; r < 8; ++r) av[r] = sm.st.A[(rg + 16*r) * 33 + d];
            bv2[0].x = sm.st.B[(cb32     ) * 33 + d];
            bv2[0].y = sm.st.B[(cb32 + 32) * 33 + d];
            bv2[1].x = sm.st.B[(cb32 + 64) * 33 + d];
            bv2[1].y = sm.st.B[(cb32 + 96) * 33 + d];
#pragma unroll
            for (int r = 0; r < 8; ++r)
#pragma unroll
                for (int j = 0; j < 2; ++j)
                    lk2[r][j] += bv2[j] * av[r];   // v_pk_fma_f32
        }
        __syncthreads();
    }

    // logK2 = -M*log2e/eps, M = ||a||^2 + ||b||^2 - 2ab (clamped >= 0)
    float lb[4];
    const float lbv = flog2((float)n1) - flog2((float)n2);
    {
        float rn1[8];
        v2f rn2[2];
#pragma unroll
        for (int r = 0; r < 8; ++r) rn1[r] = sm.st.nA[rg + 16*r];
        rn2[0].x = sm.st.nB[cb32];      rn2[0].y = sm.st.nB[cb32 + 32];
        rn2[1].x = sm.st.nB[cb32 + 64]; rn2[1].y = sm.st.nB[cb32 + 96];
#pragma unroll
        for (int r = 0; r < 8; ++r)
#pragma unroll
            for (int j = 0; j < 2; ++j) {
                v2f M2 = rn1[r] + rn2[j] - 2.f * lk2[r][j];
                lk2[r][j].x = fmaxf(M2.x, 0.f) * LKSC;
                lk2[r][j].y = fmaxf(M2.y, 0.f) * LKSC;
            }
#pragma unroll
        for (int c = 0; c < 4; ++c)
            lb[c] = (cb32 + 32*c < n2) ? lbv : NEG2;
    }
    __syncthreads();   // retire staging view of the union

    const int   crow   = tid >> 2;                  // coop-combine row 0..127
    const int   q      = tid & 3;
    const float lacrow = (crow < n1) ? 0.f : NEG2;

    float uloc[8], v[4];
#pragma unroll
    for (int r = 0; r < 8; ++r) uloc[r] = 0.f;

    // ================= Phase 1: KLOG log-domain iterations =================
    for (int k = 0; k < KLOG; ++k) {
        float mx[4], sc[4];
#pragma unroll
        for (int c = 0; c < 4; ++c) mx[c] = LK(0, c) + uloc[0];
#pragma unroll
        for (int r = 1; r < 8; ++r)
#pragma unroll
            for (int c = 0; c < 4; ++c)
                mx[c] = fmaxf(mx[c], LK(r, c) + uloc[r]);
#pragma unroll
        for (int c = 0; c < 4; ++c) {
            mx[c] = fmaxf(mx[c], __shfl_xor(mx[c], 4));
            mx[c] = fmaxf(mx[c], __shfl_xor(mx[c], 8));
            mx[c] = fmaxf(mx[c], __shfl_xor(mx[c], 16));
            mx[c] = fmaxf(mx[c], __shfl_xor(mx[c], 32));
        }
#pragma unroll
        for (int c = 0; c < 4; ++c) sc[c] = fexp2(LK(0, c) + uloc[0] - mx[c]);
#pragma unroll
        for (int r = 1; r < 8; ++r)
#pragma unroll
            for (int c = 0; c < 4; ++c)
                sc[c] += fexp2(LK(r, c) + uloc[r] - mx[c]);
#pragma unroll
        for (int c = 0; c < 4; ++c) {
            sc[c] += __shfl_xor(sc[c], 4);
            sc[c] += __shfl_xor(sc[c], 8);
            sc[c] += __shfl_xor(sc[c], 16);
            sc[c] += __shfl_xor(sc[c], 32);
        }
#pragma unroll
        for (int c = 0; c < 4; ++c)
            v[c] = lb[c] - (mx[c] + flog2(sc[c]));

#pragma unroll
        for (int r = 0; r < 8; ++r) {
            float mr = LK(r, 0) + v[0];
#pragma unroll
            for (int c = 1; c < 4; ++c) mr = fmaxf(mr, LK(r, c) + v[c]);
            mr = fmaxf(mr, __shfl_xor(mr, 1));
            mr = fmaxf(mr, __shfl_xor(mr, 2));
            float sr = fexp2(LK(r, 0) + v[0] - mr);
#pragma unroll
            for (int c = 1; c < 4; ++c) sr += fexp2(LK(r, c) + v[c] - mr);
            sr += __shfl_xor(sr, 1);
            sr += __shfl_xor(sr, 2);
            if ((r & 3) == cg)
                sm.sk.plog[(rg + 16*r) * 10 + w] = make_float2(mr, sr);
        }
        __syncthreads();                               // B1

        {   // cooperative combine: 4 lanes per row fold 8 (m,s) partials
            float4 t = *(const float4*)&sm.sk.plog[crow * 10 + 2 * q];
            float m = fmaxf(t.x, t.z);
            float s = t.y * fexp2(t.x - m) + t.w * fexp2(t.z - m);
            float mo = __shfl_xor(m, 1), so = __shfl_xor(s, 1);
            float mm = fmaxf(m, mo);
            s = s * fexp2(m - mm) + so * fexp2(mo - mm); m = mm;
            mo = __shfl_xor(m, 2); so = __shfl_xor(s, 2);
            mm = fmaxf(m, mo);
            s = s * fexp2(m - mm) + so * fexp2(mo - mm); m = mm;
            if (q == 0) sm.sk.ulog[crow] = lacrow - (m + flog2(s));
        }
        __syncthreads();                               // B2

#pragma unroll
        for (int r = 0; r < 8; ++r) uloc[r] = sm.sk.ulog[rg + 16*r];
    }

    // ============== Transition: Q = exp2(lk + u + v) =======================
    v2f Q2[8][2];
#pragma unroll
    for (int r = 0; r < 8; ++r)
#pragma unroll
        for (int j = 0; j < 2; ++j) {
            Q2[r][j].x = fexp2(LK(r, 2*j    ) + uloc[r] + v[2*j    ]);
            Q2[r][j].y = fexp2(LK(r, 2*j + 1) + uloc[r] + v[2*j + 1]);
        }

    const float bmulv = (float)n1 / (float)n2;   // beta for valid cols
    float fm[4];
#pragma unroll
    for (int c = 0; c < 4; ++c)
        fm[c] = (cb32 + 32*c < n2) ? bmulv : 0.f;
    const float gmask = (crow < n1) ? 1.f : 0.f;

    float gl[8];
#pragma unroll
    for (int r = 0; r < 8; ++r) gl[r] = 1.f;

    // ============== Phase 2: multiplicative Sinkhorn (lazy g) ==============
    // col: s_c = sum_r g_r Q[r][c]; f_c = beta_c / s_c
    // row: t_r = sum_c f_c Q[r][c]; g_r = alpha_r / t_r
    // only Q *= f is materialized; plan = diag(g) Q; fold g in every 16 iters
    // to bound Q's cumulative column drift far below fp32 overflow.
    for (int k = KLOG; k < MAX_ITERS; ++k) {
        v2f s20; s20.x = 0.f; s20.y = 0.f;
        v2f s21 = s20;
#pragma unroll
        for (int r = 0; r < 8; ++r) {
            s20 += Q2[r][0] * gl[r];   // v_pk_fma_f32
            s21 += Q2[r][1] * gl[r];
        }
        float s[4] = { s20.x, s20.y, s21.x, s21.y };
#pragma unroll
        for (int c = 0; c < 4; ++c) {
            s[c] += __shfl_xor(s[c], 4);
            s[c] += __shfl_xor(s[c], 8);
            s[c] += __shfl_xor(s[c], 16);
            s[c] += __shfl_xor(s[c], 32);
        }
        v2f f2[2];
        f2[0].x = fm[0] * frcp(fmaxf(s[0], 1e-37f));
        f2[0].y = fm[1] * frcp(fmaxf(s[1], 1e-37f));
        f2[1].x = fm[2] * frcp(fmaxf(s[2], 1e-37f));
        f2[1].y = fm[3] * frcp(fmaxf(s[3], 1e-37f));

#pragma unroll
        for (int r = 0; r < 8; ++r) {
            v2f tt = Q2[r][0] * f2[0];
            tt += Q2[r][1] * f2[1];
            float t = tt.x + tt.y;
            t += __shfl_xor(t, 1);
            t += __shfl_xor(t, 2);
            if ((r & 3) == cg)
                sm.sk.pmul[(rg + 16*r) * 10 + w] = t;
        }
        __syncthreads();                               // B1

        {
            float2 t2 = *(const float2*)&sm.sk.pmul[crow * 10 + 2 * q];
            float t = t2.x + t2.y;
            t += __shfl_xor(t, 1);
            t += __shfl_xor(t, 2);
            float gg = gmask * frcp(fmaxf(t, 1e-37f));
            if (q == 0) sm.sk.g[crow] = gg;
        }
        __syncthreads();                               // B2

#pragma unroll
        for (int r = 0; r < 8; ++r) {
            Q2[r][0] *= f2[0];
            Q2[r][1] *= f2[1];
        }
#pragma unroll
        for (int r = 0; r < 8; ++r) gl[r] = sm.sk.g[rg + 16*r];

        if ((k & 15) == 15) {   // fold pending row scale into Q (bounds drift)
#pragma unroll
            for (int r = 0; r < 8; ++r) {
                Q2[r][0] *= gl[r];
                Q2[r][1] *= gl[r];
                gl[r] = 1.f;
            }
        }
    }

    // ---- epilogue: out_b = OUTSC * sum_ij lk_ij * (g_r Q_ij) ----
    v2f acc2; acc2.x = 0.f; acc2.y = 0.f;
#pragma unroll
    for (int r = 0; r < 8; ++r)
#pragma unroll
        for (int j = 0; j < 2; ++j)
            acc2 += lk2[r][j] * (Q2[r][j] * gl[r]);
    float acc = acc2.x + acc2.y;
#pragma unroll
    for (int d = 1; d < 64; d <<= 1) acc += __shfl_xor(acc, d);
    if (lane == 0) swred[w] = acc;
    __syncthreads();
    if (tid == 0) {
        float s = 0.f;
#pragma unroll
        for (int i = 0; i < 8; ++i) s += swred[i];
        out[b] = s * OUTSC;
    }
}

extern "C" void kernel_launch(void* const* d_in, const int* in_sizes, int n_in,
                              void* d_out, int out_size, void* d_ws, size_t ws_size,
                              hipStream_t stream) {
    const float* x1  = (const float*)d_in[0];
    const float* x2  = (const float*)d_in[1];
    const int*   sz1 = (const int*)d_in[2];
    const int*   sz2 = (const int*)d_in[3];
    float* out = (float*)d_out;
    hipLaunchKernelGGL(wasserstein_kernel, dim3(512), dim3(512), 0, stream,
                       x1, x2, sz1, sz2, out);
}